// Round 4
// baseline (1644.962 us; speedup 1.0000x reference)
//
#include <hip/hip_runtime.h>

typedef _Float16 half8 __attribute__((ext_vector_type(8)));
typedef float f32x4 __attribute__((ext_vector_type(4)));

#define TT 48
#define BT 8
#define NSEQ 16384
#define NBLK (NSEQ / BT)
#define NTHR 512

struct __align__(16) Smem {
  _Float16 h0[TT][BT][136];    // 104448 B  layer-0 output history (f16)
  float gates[272][9];         //   9792 B  gate pre-activations (one dir at a time)
  _Float16 A[16][232];         //   7424 B  A panel (L0 view: [16][136])
  float yred[8][8][5];         //   1280 B  per-wave FC partials
};                             // 122944 B dynamic LDS

__device__ __forceinline__ float fast_rcp(float x) { return __builtin_amdgcn_rcpf(x); }
__device__ __forceinline__ float sigm(float x)  { return fast_rcp(1.f + __expf(-x)); }
__device__ __forceinline__ float tanh_s(float x){ return 1.f - 2.f * fast_rcp(1.f + __expf(2.f * x)); }

// One (layer, dir) recurrence, all 8 waves cooperating.
template <int LAYER>
__device__ __forceinline__ void phase(Smem& s, const int d,
    const float* __restrict__ Wih, const float* __restrict__ Whh,
    const float* __restrict__ bih, const float* __restrict__ bhh,
    const float* __restrict__ x,   const float* __restrict__ fcw,
    const int blk, float (&yk0)[5], float (&yk1)[5])
{
  constexpr int IN = (LAYER == 0) ? 34 : 136;   // non-recurrent input width
  constexpr int KS = (LAYER == 0) ? 4 : 7;      // K-steps of 32 (K = 128 / 224)
  constexpr int AW = (LAYER == 0) ? 136 : 232;  // A panel row stride (f16)
  const int tid = threadIdx.x;
  const int ln  = tid & 63;
  const int w   = tid >> 6;
  const int NT    = (w == 0) ? 3 : 2;            // N-tiles owned (17 total over 8 waves)
  const int tbase = (w == 0) ? 0 : (2 * w + 1);  // w0:0-2, w1:3-4, ..., w7:15-16
  _Float16 (*A)[AW] = (_Float16(*)[AW])&s.A[0][0];

  // ---- B fragments in registers for all 48 steps (<= 3*KS*4 = 84 VGPR) ----
  // B[k][n]: col n = ln%16, k = (ln/16)*8 + j. k<IN -> Wih, k<IN+68 -> Whh, else 0.
  half8 Bf[3][KS];
  #pragma unroll
  for (int i = 0; i < 3; ++i) if (i < NT) {
    const int g = (tbase + i) * 16 + (ln & 15);
    #pragma unroll
    for (int kk = 0; kk < KS; ++kk) {
      const int k0 = kk * 32 + ((ln >> 4) & 3) * 8;
      half8 v;
      #pragma unroll
      for (int j = 0; j < 8; ++j) {
        const int k = k0 + j;
        float wv = 0.f;
        if (k < IN) wv = Wih[g * IN + k];
        else if (k < IN + 68) wv = Whh[g * 68 + (k - IN)];
        v[j] = (_Float16)wv;
      }
      Bf[i][kk] = v;
    }
  }

  // ---- (j,b) pair ownership: 544 pairs = 512 lanes + wave-7-upper extras ----
  const int j0 = tid >> 3, b0 = tid & 7;
  const bool ep = (tid >= 480);                 // wave 7 lanes 32-63: second pair
  const int j1 = 64 + ((tid - 480) >> 3);       // j 64-67, same b0
  float bs0[4], bs1[4];
  #pragma unroll
  for (int m = 0; m < 4; ++m) bs0[m] = bih[m * 68 + j0] + bhh[m * 68 + j0];
  if (ep) {
    #pragma unroll
    for (int m = 0; m < 4; ++m) bs1[m] = bih[m * 68 + j1] + bhh[m * 68 + j1];
  }
  float c0 = 0.f, c1 = 0.f;

  // ---- zero A panel (pad rows/cols must be 0), then stage step-0 input ----
  {
    uint4* z = (uint4*)&s.A[0][0];
    if (tid < (int)(sizeof(s.A) / 16)) z[tid] = (uint4){0, 0, 0, 0};
  }
  __syncthreads();
  const int t0 = d ? (TT - 1) : 0;
  if constexpr (LAYER == 0) {
    if (tid < BT * 34) {
      const int b = tid / 34, i = tid % 34;
      A[b][i] = (_Float16)x[((size_t)(blk * BT + b) * TT + t0) * 34 + i];
    }
  } else {
    if (tid < 136) {
      const int b = tid / 17, ch = tid % 17;
      *(uint4*)&A[b][ch * 8] = *(const uint4*)&s.h0[t0][b][ch * 8];
    }
  }
  __syncthreads();

  #pragma unroll 1
  for (int st = 0; st < TT; ++st) {
    const int t  = d ? (TT - 1 - st) : st;
    const int tn = d ? (t - 1) : (t + 1);

    // prefetch next-step x (L0) / this-step fcw slice (L1)
    float xpf = 0.f;
    if constexpr (LAYER == 0) {
      if (st < TT - 1 && tid < BT * 34) {
        const int b = tid / 34, i = tid % 34;
        xpf = x[((size_t)(blk * BT + b) * TT + tn) * 34 + i];
      }
    }
    float fw0[5], fw1[5];
    if constexpr (LAYER == 1) {
      #pragma unroll
      for (int k = 0; k < 5; ++k) fw0[k] = fcw[k * 6528 + t * 136 + d * 68 + j0];
      if (ep) {
        #pragma unroll
        for (int k = 0; k < 5; ++k) fw1[k] = fcw[k * 6528 + t * 136 + d * 68 + j1];
      }
    }

    // ---- MFMA: gates(8x272) = A(8xK) . B(Kx272), 2-3 tiles per wave ----
    f32x4 acc[3];
    #pragma unroll
    for (int i = 0; i < 3; ++i) acc[i] = (f32x4){0.f, 0.f, 0.f, 0.f};
    #pragma unroll
    for (int kk = 0; kk < KS; ++kk) {
      const half8 a = *(const half8*)&A[ln & 15][kk * 32 + ((ln >> 4) & 3) * 8];
      #pragma unroll
      for (int i = 0; i < 3; ++i) if (i < NT)
        acc[i] = __builtin_amdgcn_mfma_f32_16x16x32_f16(a, Bf[i][kk], acc[i], 0, 0, 0);
    }
    // C/D: col = lane&15, row = (lane>>4)*4 + r; only rows 0-7 are real (M=8)
    if (ln < 32) {
      #pragma unroll
      for (int i = 0; i < 3; ++i) if (i < NT) {
        const int g = (tbase + i) * 16 + (ln & 15);
        #pragma unroll
        for (int r = 0; r < 4; ++r)
          s.gates[g][(ln >> 4) * 4 + r] = acc[i][r];
      }
    }
    __syncthreads();

    // ---- cell update: pair 0 (all lanes) ----
    {
      const float gi = s.gates[j0][b0] + bs0[0];
      const float gf = s.gates[68 + j0][b0] + bs0[1];
      const float gg = s.gates[136 + j0][b0] + bs0[2];
      const float go = s.gates[204 + j0][b0] + bs0[3];
      const float ii = sigm(gi), ff = sigm(gf), g2 = tanh_s(gg), oo = sigm(go);
      const float c = ff * c0 + ii * g2; c0 = c;
      const float h = oo * tanh_s(c);
      const _Float16 hh = (_Float16)h;
      if constexpr (LAYER == 0) {
        A[b0][34 + j0] = hh;
        s.h0[t][b0][d * 68 + j0] = hh;
      } else {
        A[b0][136 + j0] = hh;
        #pragma unroll
        for (int k = 0; k < 5; ++k) yk0[k] += h * fw0[k];
      }
    }
    // ---- cell update: pair 1 (wave-7 upper lanes, j 64-67) ----
    if (ep) {
      const float gi = s.gates[j1][b0] + bs1[0];
      const float gf = s.gates[68 + j1][b0] + bs1[1];
      const float gg = s.gates[136 + j1][b0] + bs1[2];
      const float go = s.gates[204 + j1][b0] + bs1[3];
      const float ii = sigm(gi), ff = sigm(gf), g2 = tanh_s(gg), oo = sigm(go);
      const float c = ff * c1 + ii * g2; c1 = c;
      const float h = oo * tanh_s(c);
      const _Float16 hh = (_Float16)h;
      if constexpr (LAYER == 0) {
        A[b0][34 + j1] = hh;
        s.h0[t][b0][d * 68 + j1] = hh;
      } else {
        A[b0][136 + j1] = hh;
        #pragma unroll
        for (int k = 0; k < 5; ++k) yk1[k] += h * fw1[k];
      }
    }
    // ---- stage next step's non-recurrent A section ----
    if constexpr (LAYER == 0) {
      if (st < TT - 1 && tid < BT * 34) {
        const int b = tid / 34, i = tid % 34;
        A[b][i] = (_Float16)xpf;
      }
    } else {
      if (st < TT - 1 && tid < 136) {
        const int b = tid / 17, ch = tid % 17;
        *(uint4*)&A[b][ch * 8] = *(const uint4*)&s.h0[tn][b][ch * 8];
      }
    }
    __syncthreads();
  }
}

__global__ __attribute__((amdgpu_flat_work_group_size(NTHR, NTHR), amdgpu_waves_per_eu(2, 2)))
void lstm_fc_mfma(
    const float* __restrict__ x,
    const float* __restrict__ Wih0f, const float* __restrict__ Whh0f,
    const float* __restrict__ bih0f, const float* __restrict__ bhh0f,
    const float* __restrict__ Wih0b, const float* __restrict__ Whh0b,
    const float* __restrict__ bih0b, const float* __restrict__ bhh0b,
    const float* __restrict__ Wih1f, const float* __restrict__ Whh1f,
    const float* __restrict__ bih1f, const float* __restrict__ bhh1f,
    const float* __restrict__ Wih1b, const float* __restrict__ Whh1b,
    const float* __restrict__ bih1b, const float* __restrict__ bhh1b,
    const float* __restrict__ fcw, const float* __restrict__ fcb,
    float* __restrict__ out)
{
  extern __shared__ char smem_raw[];
  Smem& s = *reinterpret_cast<Smem*>(smem_raw);
  const int tid = threadIdx.x;
  const int blk = blockIdx.x;
  const int ln = tid & 63, w = tid >> 6;

  float yk0[5], yk1[5];
  #pragma unroll
  for (int k = 0; k < 5; ++k) { yk0[k] = 0.f; yk1[k] = 0.f; }

  phase<0>(s, 0, Wih0f, Whh0f, bih0f, bhh0f, x, nullptr, blk, yk0, yk1);
  phase<0>(s, 1, Wih0b, Whh0b, bih0b, bhh0b, x, nullptr, blk, yk0, yk1);
  phase<1>(s, 0, Wih1f, Whh1f, bih1f, bhh1f, nullptr, fcw, blk, yk0, yk1);
  phase<1>(s, 1, Wih1b, Whh1b, bih1b, bhh1b, nullptr, fcw, blk, yk0, yk1);

  // ---- FC reduction: fold extra pair, butterfly over j-octets, LDS combine ----
  const bool ep = (tid >= 480);
  float ys[5];
  #pragma unroll
  for (int k = 0; k < 5; ++k) ys[k] = yk0[k] + (ep ? yk1[k] : 0.f);
  #pragma unroll
  for (int m = 8; m <= 32; m <<= 1) {
    #pragma unroll
    for (int k = 0; k < 5; ++k) ys[k] += __shfl_xor(ys[k], m, 64);
  }
  if (ln < 8) {
    #pragma unroll
    for (int k = 0; k < 5; ++k) s.yred[w][ln][k] = ys[k];
  }
  __syncthreads();

  if (tid < BT * 5) {
    const int b = tid / 5, k = tid % 5;
    float v = fcb[k];
    #pragma unroll
    for (int w8 = 0; w8 < 8; ++w8) v += s.yred[w8][b][k];
    out[((size_t)blk * BT + b) * 5 + k] = v;
  }
}

extern "C" void kernel_launch(void* const* d_in, const int* in_sizes, int n_in,
                              void* d_out, int out_size, void* d_ws, size_t ws_size,
                              hipStream_t stream) {
  (void)in_sizes; (void)n_in; (void)d_ws; (void)ws_size; (void)out_size;
  static_assert(sizeof(Smem) <= 160 * 1024, "LDS overflow");
  hipFuncSetAttribute((const void*)lstm_fc_mfma,
                      hipFuncAttributeMaxDynamicSharedMemorySize, (int)sizeof(Smem));

  const float* x     = (const float*)d_in[0];
  const float* Wih0f = (const float*)d_in[1];
  const float* Whh0f = (const float*)d_in[2];
  const float* bih0f = (const float*)d_in[3];
  const float* bhh0f = (const float*)d_in[4];
  const float* Wih0b = (const float*)d_in[5];
  const float* Whh0b = (const float*)d_in[6];
  const float* bih0b = (const float*)d_in[7];
  const float* bhh0b = (const float*)d_in[8];
  const float* Wih1f = (const float*)d_in[9];
  const float* Whh1f = (const float*)d_in[10];
  const float* bih1f = (const float*)d_in[11];
  const float* bhh1f = (const float*)d_in[12];
  const float* Wih1b = (const float*)d_in[13];
  const float* Whh1b = (const float*)d_in[14];
  const float* bih1b = (const float*)d_in[15];
  const float* bhh1b = (const float*)d_in[16];
  const float* fcw   = (const float*)d_in[17];
  const float* fcb   = (const float*)d_in[18];
  float* out = (float*)d_out;

  lstm_fc_mfma<<<dim3(NBLK), dim3(NTHR), sizeof(Smem), stream>>>(x,
      Wih0f, Whh0f, bih0f, bhh0f, Wih0b, Whh0b, bih0b, bhh0b,
      Wih1f, Whh1f, bih1f, bhh1f, Wih1b, Whh1b, bih1b, bhh1b,
      fcw, fcb, out);
}

// Round 5
// 1468.843 us; speedup vs baseline: 1.1199x; 1.1199x over previous
//
#include <hip/hip_runtime.h>

typedef _Float16 half8 __attribute__((ext_vector_type(8)));
typedef float f32x4 __attribute__((ext_vector_type(4)));

#define TT 48
#define BT 16
#define NSEQ 16384
#define NGRP (NSEQ / BT)          // 1024 sequence groups
#define NTHR 512
#define MAXGRID 512
#define H0_SLICE (TT * BT * 136)  // f16 elems per block ws slice (208896 B)

struct __align__(16) Smem {
  float gates[2][272][17];   // 36992 B [dir][gate][batch+pad]; stride 17 dwords (odd -> bank spread)
  _Float16 A[2][16][232];    // 14848 B A panels; L0 view reinterpreted as [16][136]
};                           // 51840 B; FC scratch (yscr, 43840 B) overlays gates+A after L1

__device__ __forceinline__ float fast_rcp(float x) { return __builtin_amdgcn_rcpf(x); }
__device__ __forceinline__ float sigm(float x)  { return fast_rcp(1.f + __expf(-x)); }
__device__ __forceinline__ float tanh_s(float x){ return 1.f - 2.f * fast_rcp(1.f + __expf(2.f * x)); }
__device__ __forceinline__ int t_of(int d, int st) { return d ? (TT - 1 - st) : st; }

// One layer, BOTH directions concurrently: waves 0-3 = fwd, waves 4-7 = bwd.
template <int LAYER>
__device__ __forceinline__ void phase(Smem& s,
    const float* __restrict__ WihF, const float* __restrict__ WhhF,
    const float* __restrict__ bihF, const float* __restrict__ bhhF,
    const float* __restrict__ WihB, const float* __restrict__ WhhB,
    const float* __restrict__ bihB, const float* __restrict__ bhhB,
    const float* __restrict__ x,    const float* __restrict__ fcw,
    _Float16* __restrict__ h0w, int grp)
{
  constexpr int IN = LAYER ? 136 : 34;    // non-recurrent input width
  constexpr int KS = LAYER ? 7 : 4;       // K-chunks of 32 (K = 224 / 128)
  constexpr int AW = LAYER ? 232 : 136;   // A panel row stride (f16)
  constexpr int BC = IN + 68;             // bias-one column (sits in former padding)
  constexpr int HOFF = LAYER ? 136 : 34;  // h slot base within A row

  const int tid = threadIdx.x;
  const int ln  = tid & 63;
  const int wid = tid >> 6;
  const int dw  = wid >> 2;               // this wave's direction
  const int wq  = wid & 3;
  const int NT    = (wq == 0) ? 5 : 4;    // N-tiles (17 per dir over 4 waves)
  const int tbase = (wq == 0) ? 0 : (1 + 4 * wq);

  const float* Wih = dw ? WihB : WihF;
  const float* Whh = dw ? WhhB : WhhF;
  const float* bih = dw ? bihB : bihF;
  const float* bhh = dw ? bhhB : bhhF;

  _Float16* Af = &s.A[0][0][0];
  float*    gf = &s.gates[0][0][0];

  // ---- B fragments in registers for all 48 steps (bias baked into column BC) ----
  half8 Bf[5][KS];
  #pragma unroll
  for (int i = 0; i < 5; ++i) if (i < NT) {
    const int g = (tbase + i) * 16 + (ln & 15);
    #pragma unroll
    for (int kk = 0; kk < KS; ++kk) {
      half8 v;
      #pragma unroll
      for (int j = 0; j < 8; ++j) {
        const int k = kk * 32 + ((ln >> 4) & 3) * 8 + j;
        float wv = 0.f;
        if (k < IN) wv = Wih[g * IN + k];
        else if (k < IN + 68) wv = Whh[g * 68 + (k - IN)];
        else if (k == BC) wv = bih[g] + bhh[g];
        v[j] = (_Float16)wv;
      }
      Bf[i][kk] = v;
    }
  }

  // ---- elementwise pair ownership: p = d*1088 + b*68 + j (j-fast => coalesced) ----
  int gq[5], ao[5], pd[5], hwb[5], yb[5];
  float c[5];
  float yk[5][5];
  #pragma unroll
  for (int q = 0; q < 5; ++q) {
    const int p = (q < 4) ? (tid + 512 * q) : (2048 + tid);
    const int d = p / 1088;
    const int r = p - d * 1088;
    const int b = r / 68;
    const int j = r - b * 68;
    pd[q]  = d;
    gq[q]  = (d * 272 + j) * 17 + b;
    ao[q]  = d * 3712 + b * AW + HOFF + j;
    hwb[q] = LAYER ? (d * 68 + j) : (b * 136 + d * 68 + j);
    yb[q]  = b * 685 + d * 68 + j;           // (b*5+k)*137 + d*68+j, k-step 137
    c[q] = 0.f;
    #pragma unroll
    for (int k = 0; k < 5; ++k) yk[q][k] = 0.f;
  }

  // ---- staging task precompute ----
  int sd[3], xo[3], sao[3], hro[2];
  if constexpr (!LAYER) {
    #pragma unroll
    for (int u = 0; u < 3; ++u) {
      const int task = tid + 512 * u;
      if (task < 1088) {
        const int d = task / 544;
        const int r = task - d * 544;
        const int b = r / 34;
        const int i = r - b * 34;
        sd[u]  = d;
        xo[u]  = ((grp * 16 + b) * 48) * 34 + i;
        sao[u] = d * 3712 + b * 136 + i;
      }
    }
  } else {
    #pragma unroll
    for (int u = 0; u < 2; ++u) {
      const int task = tid + 512 * u;
      if (task < 544) {
        const int d = task / 272;
        const int r = task - d * 272;
        const int b = r / 17;
        const int ch = r - b * 17;
        sd[u]  = d;
        hro[u] = b * 136 + ch * 8;           // + t*2176 per step
        sao[u] = d * 3712 + b * 232 + ch * 8;
      }
    }
  }

  // ---- prologue: zero A, set bias-one columns, stage step 0 ----
  {
    uint4* z = (uint4*)Af;
    const uint4 zz = {0, 0, 0, 0};
    z[tid] = zz;
    if (tid < 416) z[tid + 512] = zz;
  }
  __syncthreads();
  if (tid < 32) Af[(tid >> 4) * 3712 + (tid & 15) * AW + BC] = (_Float16)1.f;
  if constexpr (!LAYER) {
    #pragma unroll
    for (int u = 0; u < 3; ++u)
      if (tid + 512 * u < 1088)
        Af[sao[u]] = (_Float16)x[xo[u] + t_of(sd[u], 0) * 34];
  } else {
    #pragma unroll
    for (int u = 0; u < 2; ++u)
      if (tid + 512 * u < 544)
        *(uint4*)&Af[sao[u]] = *(const uint4*)&h0w[hro[u] + t_of(sd[u], 0) * 2176];
  }
  __syncthreads();

  #pragma unroll 1
  for (int st = 0; st < TT; ++st) {
    // ---- prefetch next-step staging into regs (hide global latency under MFMA) ----
    float xpf[3]; uint4 hpf[2];
    if (st < TT - 1) {
      if constexpr (!LAYER) {
        #pragma unroll
        for (int u = 0; u < 3; ++u)
          if (tid + 512 * u < 1088)
            xpf[u] = x[xo[u] + t_of(sd[u], st + 1) * 34];
      } else {
        #pragma unroll
        for (int u = 0; u < 2; ++u)
          if (tid + 512 * u < 544)
            hpf[u] = *(const uint4*)&h0w[hro[u] + t_of(sd[u], st + 1) * 2176];
      }
    }

    // ---- MFMA: gates(16x272) = A(16xK) . B(Kx272) per direction ----
    f32x4 acc[5];
    #pragma unroll
    for (int i = 0; i < 5; ++i) acc[i] = (f32x4){0.f, 0.f, 0.f, 0.f};
    #pragma unroll
    for (int kk = 0; kk < KS; ++kk) {
      const half8 a = *(const half8*)&Af[dw * 3712 + (ln & 15) * AW + kk * 32 + ((ln >> 4) & 3) * 8];
      #pragma unroll
      for (int i = 0; i < 5; ++i) if (i < NT)
        acc[i] = __builtin_amdgcn_mfma_f32_16x16x32_f16(a, Bf[i][kk], acc[i], 0, 0, 0);
    }
    // C/D: col = lane&15 (gate), row = (lane>>4)*4 + r (batch 0..15)
    #pragma unroll
    for (int i = 0; i < 5; ++i) if (i < NT) {
      const int g = (tbase + i) * 16 + (ln & 15);
      #pragma unroll
      for (int r = 0; r < 4; ++r)
        gf[(dw * 272 + g) * 17 + ((ln >> 4) & 3) * 4 + r] = acc[i][r];
    }
    __syncthreads();

    // ---- elementwise cell update (bias already in gates via 1-column) ----
    #pragma unroll
    for (int q = 0; q < 5; ++q) {
      if (q < 4 || tid < 128) {
        const float gi = gf[gq[q]];
        const float gfr = gf[gq[q] + 1156];
        const float gg = gf[gq[q] + 2312];
        const float go = gf[gq[q] + 3468];
        const float ii = sigm(gi), ff = sigm(gfr), g2 = tanh_s(gg), oo = sigm(go);
        const float cc = ff * c[q] + ii * g2;
        c[q] = cc;
        const float h = oo * tanh_s(cc);
        const _Float16 h16 = (_Float16)h;
        Af[ao[q]] = h16;
        const int tq = pd[q] ? (TT - 1 - st) : st;
        if constexpr (!LAYER) {
          h0w[tq * 2176 + hwb[q]] = h16;       // coalesced: j-fast lanes
        } else {
          const int fbase = tq * 136 + hwb[q];
          #pragma unroll
          for (int k = 0; k < 5; ++k)
            yk[q][k] += h * fcw[k * 6528 + fbase];
        }
      }
    }
    // ---- staging writes for next step ----
    if (st < TT - 1) {
      if constexpr (!LAYER) {
        #pragma unroll
        for (int u = 0; u < 3; ++u)
          if (tid + 512 * u < 1088) Af[sao[u]] = (_Float16)xpf[u];
      } else {
        #pragma unroll
        for (int u = 0; u < 2; ++u)
          if (tid + 512 * u < 544) *(uint4*)&Af[sao[u]] = hpf[u];
      }
    }
    __syncthreads();
  }

  // ---- L1 epilogue: deterministic FC partial dump into LDS scratch ----
  if constexpr (LAYER) {
    #pragma unroll
    for (int q = 0; q < 5; ++q) if (q < 4 || tid < 128) {
      #pragma unroll
      for (int k = 0; k < 5; ++k)
        gf[yb[q] + k * 137] = yk[q][k];
    }
  }
}

__global__ __attribute__((amdgpu_flat_work_group_size(NTHR, NTHR), amdgpu_waves_per_eu(2, 2)))
void lstm_fc_mfma(
    const float* __restrict__ x,
    const float* __restrict__ Wih0f, const float* __restrict__ Whh0f,
    const float* __restrict__ bih0f, const float* __restrict__ bhh0f,
    const float* __restrict__ Wih0b, const float* __restrict__ Whh0b,
    const float* __restrict__ bih0b, const float* __restrict__ bhh0b,
    const float* __restrict__ Wih1f, const float* __restrict__ Whh1f,
    const float* __restrict__ bih1f, const float* __restrict__ bhh1f,
    const float* __restrict__ Wih1b, const float* __restrict__ Whh1b,
    const float* __restrict__ bih1b, const float* __restrict__ bhh1b,
    const float* __restrict__ fcw, const float* __restrict__ fcb,
    float* __restrict__ out, _Float16* __restrict__ ws)
{
  extern __shared__ char smem_raw[];
  Smem& s = *reinterpret_cast<Smem*>(smem_raw);
  _Float16* h0w = ws + (size_t)blockIdx.x * H0_SLICE;

  for (int grp = blockIdx.x; grp < NGRP; grp += gridDim.x) {
    phase<0>(s, Wih0f, Whh0f, bih0f, bhh0f, Wih0b, Whh0b, bih0b, bhh0b,
             x, nullptr, h0w, grp);
    phase<1>(s, Wih1f, Whh1f, bih1f, bhh1f, Wih1b, Whh1b, bih1b, bhh1b,
             nullptr, fcw, h0w, grp);
    __syncthreads();
    if (threadIdx.x < 80) {
      const int b = threadIdx.x / 5, k = threadIdx.x - b * 5;
      const float* yscr = &s.gates[0][0][0];
      float v = fcb[k];
      #pragma unroll 8
      for (int m = 0; m < 136; ++m) v += yscr[threadIdx.x * 137 + m];
      out[(size_t)(grp * 16 + b) * 5 + k] = v;
    }
    __syncthreads();   // protect yscr/gates before next group's reuse
  }
}

extern "C" void kernel_launch(void* const* d_in, const int* in_sizes, int n_in,
                              void* d_out, int out_size, void* d_ws, size_t ws_size,
                              hipStream_t stream) {
  (void)in_sizes; (void)n_in; (void)out_size;
  static_assert(sizeof(Smem) <= 64 * 1024, "LDS overflow");
  hipFuncSetAttribute((const void*)lstm_fc_mfma,
                      hipFuncAttributeMaxDynamicSharedMemorySize, (int)sizeof(Smem));

  const float* x     = (const float*)d_in[0];
  const float* Wih0f = (const float*)d_in[1];
  const float* Whh0f = (const float*)d_in[2];
  const float* bih0f = (const float*)d_in[3];
  const float* bhh0f = (const float*)d_in[4];
  const float* Wih0b = (const float*)d_in[5];
  const float* Whh0b = (const float*)d_in[6];
  const float* bih0b = (const float*)d_in[7];
  const float* bhh0b = (const float*)d_in[8];
  const float* Wih1f = (const float*)d_in[9];
  const float* Whh1f = (const float*)d_in[10];
  const float* bih1f = (const float*)d_in[11];
  const float* bhh1f = (const float*)d_in[12];
  const float* Wih1b = (const float*)d_in[13];
  const float* Whh1b = (const float*)d_in[14];
  const float* bih1b = (const float*)d_in[15];
  const float* bhh1b = (const float*)d_in[16];
  const float* fcw   = (const float*)d_in[17];
  const float* fcb   = (const float*)d_in[18];
  float* out = (float*)d_out;

  // one h0-history slice (208896 B) per block; degrade grid if ws is small
  int slices = (int)(ws_size / (size_t)(H0_SLICE * 2));
  int grid = slices < 1 ? 1 : (slices > MAXGRID ? MAXGRID : slices);

  lstm_fc_mfma<<<dim3(grid), dim3(NTHR), sizeof(Smem), stream>>>(x,
      Wih0f, Whh0f, bih0f, bhh0f, Wih0b, Whh0b, bih0b, bhh0b,
      Wih1f, Whh1f, bih1f, bhh1f, Wih1b, Whh1b, bih1b, bhh1b,
      fcw, fcb, out, (_Float16*)d_ws);
}